// Round 7
// baseline (194.815 us; speedup 1.0000x reference)
//
#include <hip/hip_runtime.h>

typedef __attribute__((ext_vector_type(8))) _Float16 f16x8;
typedef __attribute__((ext_vector_type(4))) _Float16 f16x4;
typedef __attribute__((ext_vector_type(2))) __fp16 fp16x2;
typedef __attribute__((ext_vector_type(4))) float f32x4;

union U8 { f16x8 v; fp16x2 p[4]; };
union U4 { f16x4 v; fp16x2 p[2]; };

__device__ __forceinline__ f16x8 cvt8(f32x4 a, f32x4 b) {
  U8 u;
  u.p[0] = __builtin_amdgcn_cvt_pkrtz(a.x, a.y);
  u.p[1] = __builtin_amdgcn_cvt_pkrtz(a.z, a.w);
  u.p[2] = __builtin_amdgcn_cvt_pkrtz(b.x, b.y);
  u.p[3] = __builtin_amdgcn_cvt_pkrtz(b.z, b.w);
  return u.v;
}
__device__ __forceinline__ f16x4 cvt4(f32x4 a) {
  U4 u;
  u.p[0] = __builtin_amdgcn_cvt_pkrtz(a.x, a.y);
  u.p[1] = __builtin_amdgcn_cvt_pkrtz(a.z, a.w);
  return u.v;
}
__device__ __forceinline__ float dot4(f32x4 a, f32x4 b) {
  return a.x * b.x + a.y * b.y + a.z * b.z + a.w * b.w;
}

// Wave-private GCN, K=32 MFMAs, aggregate-before-matmul (1x FLOPs):
//   out[n] = W . (ca*h[n] + cb*(h[m1]+h[m2]))  -- agg in f16 B-frag space.
// Inter-layer transpose via wave-private 12KB LDS tile [node][8B-slot][batch]:
// conflict-free writes (4 contiguous rows) and reads (banks keyed by c only),
// no swizzle, no barriers (same-wave DS ops are in-order).
__global__ __launch_bounds__(256, 3) void gcn_fused(
    const float* __restrict__ x,
    const float* __restrict__ W1, const float* __restrict__ B1,
    const float* __restrict__ W2, const float* __restrict__ B2,
    const float* __restrict__ W3, const float* __restrict__ B3,
    const float* __restrict__ W4, const float* __restrict__ B4,
    const float* __restrict__ fcw, const float* __restrict__ fcb,
    float* __restrict__ out)
{
  // [wave][node][slot 0..15][batch 0..15][4 f16]  (8B granules)
  __shared__ __align__(16) _Float16 xs[4][6][16][16][4];

  const int tid  = threadIdx.x;
  const int lane = tid & 63;
  const int w    = tid >> 6;
  const int c    = lane & 15;   // batch col / A-row / C-col
  const int q    = lane >> 4;   // k-group / C row-group
  const int b    = blockIdx.x * 64 + w * 16 + c;   // this lane's batch row

  const int NB0[6] = {1, 0, 1, 2, 3, 3};
  const int NB1[6] = {2, 2, 3, 4, 5, 4};
  const float* Ws[4] = {W1, W2, W3, W4};
  const float* Bs[4] = {B1, B2, B3, B4};

  _Float16* hl = &xs[w][0][0][0][0];

  // ---- x -> layer-1 B-frags (registers) + residual fc-dot q-partials ----
  f16x8 hb[6][2];
  float pacc[6];
  {
    const float* xr = x + (size_t)b * 384 + q * 8;
#pragma unroll
    for (int n = 0; n < 6; ++n) {
      float p = 0.f;
#pragma unroll
      for (int kf = 0; kf < 2; ++kf) {
        f32x4 v0 = *(const f32x4*)(xr + n * 64 + kf * 32);
        f32x4 v1 = *(const f32x4*)(xr + n * 64 + kf * 32 + 4);
        const float* fw = fcw + n * 64 + kf * 32 + q * 8;
        p += dot4(v0, *(const f32x4*)fw) + dot4(v1, *(const f32x4*)(fw + 4));
        hb[n][kf] = cvt8(v0, v1);
      }
      pacc[n] = p;  // partial over this lane's k-slice; reduced in epilogue
    }
  }

#pragma unroll
  for (int l = 0; l < 4; ++l) {
    // W as A-frags (unscaled): lane(c,q): row=c(+16nt), k=kf*32+8q+j
    f16x8 wf[4][2];
#pragma unroll
    for (int nt = 0; nt < 4; ++nt)
#pragma unroll
      for (int kf = 0; kf < 2; ++kf) {
        const float* wp = Ws[l] + (nt * 16 + c) * 64 + kf * 32 + q * 8;
        wf[nt][kf] = cvt8(*(const f32x4*)wp, *(const f32x4*)(wp + 4));
      }
    f32x4 bval[4];
#pragma unroll
    for (int nt = 0; nt < 4; ++nt)
      bval[nt] = *(const f32x4*)(Bs[l] + nt * 16 + q * 4);  // bias rows 16nt+4q+e

    if (l > 0) {
      // read h from LDS as B-frags: slots 8kf+2q, 8kf+2q+1 at batch col c
#pragma unroll
      for (int n = 0; n < 6; ++n)
#pragma unroll
        for (int kf = 0; kf < 2; ++kf) {
          f16x4 lo = *(const f16x4*)&hl[((n * 16 + 8 * kf + 2 * q) * 16 + c) * 4];
          f16x4 hi = *(const f16x4*)&hl[((n * 16 + 8 * kf + 2 * q + 1) * 16 + c) * 4];
          hb[n][kf] = __builtin_shufflevector(lo, hi, 0, 1, 2, 3, 4, 5, 6, 7);
        }
    }

    const _Float16 cbs = (_Float16)((l < 2) ? (1.f / 3.f) : 0.25f);
    const f16x8 cbv = {cbs, cbs, cbs, cbs, cbs, cbs, cbs, cbs};

#pragma unroll
    for (int n = 0; n < 6; ++n) {
      const int m1 = NB0[n], m2 = NB1[n];
      // aggregate in f16 (packed VALU): ca*self + cb*(m1+m2); ca=cb (l<2), ca=2cb (l>=2)
      f16x8 ag[2];
#pragma unroll
      for (int kf = 0; kf < 2; ++kf) {
        f16x8 s = hb[n][kf] + hb[m1][kf] + hb[m2][kf];
        if (l >= 2) s = s + hb[n][kf];
        ag[kf] = s * cbv;
      }
      f32x4 acc[4];
#pragma unroll
      for (int nt = 0; nt < 4; ++nt) acc[nt] = bval[nt];
#pragma unroll
      for (int nt = 0; nt < 4; ++nt) {
        acc[nt] = __builtin_amdgcn_mfma_f32_16x16x32_f16(wf[nt][0], ag[0], acc[nt], 0, 0, 0);
        acc[nt] = __builtin_amdgcn_mfma_f32_16x16x32_f16(wf[nt][1], ag[1], acc[nt], 0, 0, 0);
      }
      if (l < 3) {
        // relu + f16, write transposed: feats 16nt+4q+e of batch c -> slot 4nt+q
#pragma unroll
        for (int nt = 0; nt < 4; ++nt) {
          f32x4 r;
#pragma unroll
          for (int e = 0; e < 4; ++e) r[e] = fmaxf(acc[nt][e], 0.f);
          *(f16x4*)&hl[((n * 16 + 4 * nt + q) * 16 + c) * 4] = cvt4(r);
        }
      } else {
        // epilogue: relu + fc-dot in f32 on C-frags, reduce over q, sigmoid
        float sv = pacc[n];
#pragma unroll
        for (int nt = 0; nt < 4; ++nt) {
          f32x4 fwv = *(const f32x4*)(fcw + n * 64 + nt * 16 + q * 4);
#pragma unroll
          for (int e = 0; e < 4; ++e) sv += fmaxf(acc[nt][e], 0.f) * fwv[e];
        }
        sv += __shfl_xor(sv, 16, 64);
        sv += __shfl_xor(sv, 32, 64);
        if (q == 0) {
          const float vz = sv + fcb[n];
          out[(size_t)b * 6 + n] = 1.f / (1.f + __expf(-vz));
        }
      }
    }
  }
}

extern "C" void kernel_launch(void* const* d_in, const int* in_sizes, int n_in,
                              void* d_out, int out_size, void* d_ws, size_t ws_size,
                              hipStream_t stream) {
  const float* x   = (const float*)d_in[0];
  const float* W1  = (const float*)d_in[1];
  const float* B1  = (const float*)d_in[2];
  const float* W2  = (const float*)d_in[3];
  const float* B2  = (const float*)d_in[4];
  const float* W3  = (const float*)d_in[5];
  const float* B3  = (const float*)d_in[6];
  const float* W4  = (const float*)d_in[7];
  const float* B4  = (const float*)d_in[8];
  const float* fcw = (const float*)d_in[9];
  const float* fcb = (const float*)d_in[10];
  float* out = (float*)d_out;

  const int batch  = in_sizes[0] / 384;   // 131072
  const int blocks = batch / 64;          // 4 waves x 16 batch rows per block
  hipLaunchKernelGGL(gcn_fused, dim3(blocks), dim3(256), 0, stream,
                     x, W1, B1, W2, B2, W3, B3, W4, B4, fcw, fcb, out);
}

// Round 8
// 178.674 us; speedup vs baseline: 1.0903x; 1.0903x over previous
//
#include <hip/hip_runtime.h>

typedef __attribute__((ext_vector_type(4))) _Float16 f16x4;
typedef __attribute__((ext_vector_type(2))) __fp16 fp16x2;
typedef __attribute__((ext_vector_type(4))) float f32x4;

union U4 { f16x4 v; fp16x2 p[2]; };

__device__ __forceinline__ f16x4 cvt4(f32x4 a) {
  U4 u;
  u.p[0] = __builtin_amdgcn_cvt_pkrtz(a.x, a.y);
  u.p[1] = __builtin_amdgcn_cvt_pkrtz(a.z, a.w);
  return u.v;
}
__device__ __forceinline__ float dot4(f32x4 a, f32x4 b) {
  return a.x * b.x + a.y * b.y + a.z * b.z + a.w * b.w;
}

#define WSTRIDE 72  // f16 row stride: 144B -> 8B-aligned b64 frags, pure 2-way banks

// Zero-data-movement GCN: wave-private 16 batch rows, K=16 MFMA B<->C chaining
// (C rows 4q+e == B k 4q+j, proven by r6 pass), aggregate-BEFORE-matmul in f16
// B-frag space (1x FLOPs):  out[n] = relu( (cb*W) . ag[n] + b ),
//   ag[n] = h[n]*(1 or 2) + h[m1] + h[m2]   (cb pre-folded into W in LDS).
// One barrier total (W staging); no inter-layer LDS, no spill-prone big state.
__global__ __launch_bounds__(256, 3) void gcn_fused(
    const float* __restrict__ x,
    const float* __restrict__ W1, const float* __restrict__ B1,
    const float* __restrict__ W2, const float* __restrict__ B2,
    const float* __restrict__ W3, const float* __restrict__ B3,
    const float* __restrict__ W4, const float* __restrict__ B4,
    const float* __restrict__ fcw, const float* __restrict__ fcb,
    float* __restrict__ out)
{
  __shared__ __align__(16) _Float16 wlds[4][64][WSTRIDE];  // cb_l * W_l

  const int tid  = threadIdx.x;
  const int lane = tid & 63;
  const int w    = tid >> 6;
  const int c    = lane & 15;   // batch col (B/C col, A row)
  const int q    = lane >> 4;   // k-group (k=4q+j) / C row-group (row=4q+e)
  const int b    = blockIdx.x * 64 + w * 16 + c;   // this lane's batch row

  const float* Wg[4] = {W1, W2, W3, W4};
  const float* Bg[4] = {B1, B2, B3, B4};
  const int NB0[6] = {1, 0, 1, 2, 3, 3};
  const int NB1[6] = {2, 2, 3, 4, 5, 4};

  // ---- stage cb_l * W_l into LDS (one time, all 4 layers) ----
#pragma unroll
  for (int l = 0; l < 4; ++l) {
    const float s = (l < 2) ? (1.f / 3.f) : 0.25f;
#pragma unroll
    for (int rep = 0; rep < 4; ++rep) {
      const int idx = rep * 1024 + tid * 4;   // flat f32 index into 64x64 W_l
      const int row = idx >> 6, col = idx & 63;
      f32x4 v = *(const f32x4*)(Wg[l] + idx);
      v *= s;
      *(f16x4*)&wlds[l][row][col] = cvt4(v);
    }
  }

  // ---- x -> layer-1 B-frags (registers) + residual fc-dot q-partials ----
  f16x4 h[6][4];   // [node][kc]: lane (c,q) holds feats kc*16+4q+j of batch b
  float pacc[6];
  {
    const float* xr = x + (size_t)b * 384 + q * 4;
#pragma unroll
    for (int n = 0; n < 6; ++n) {
      float p = 0.f;
#pragma unroll
      for (int kc = 0; kc < 4; ++kc) {
        f32x4 v  = *(const f32x4*)(xr + n * 64 + kc * 16);
        f32x4 fw = *(const f32x4*)(fcw + n * 64 + kc * 16 + q * 4);
        p += dot4(v, fw);
        h[n][kc] = cvt4(v);
      }
      pacc[n] = p;  // partial over this lane's 16 k-values; reduced at epilogue
    }
  }
  __syncthreads();  // W staging visible; no further barriers

#pragma unroll
  for (int l = 0; l < 4; ++l) {
    // W A-frags from LDS: lane (c,q): row = nt*16+c, k = kc*16+4q+j
    f16x4 wf[4][4];
#pragma unroll
    for (int nt = 0; nt < 4; ++nt)
#pragma unroll
      for (int kc = 0; kc < 4; ++kc)
        wf[nt][kc] = *(const f16x4*)&wlds[l][nt * 16 + c][kc * 16 + q * 4];
    f32x4 bval[4];
#pragma unroll
    for (int nt = 0; nt < 4; ++nt)
      bval[nt] = *(const f32x4*)(Bg[l] + nt * 16 + q * 4);  // bias rows nt*16+4q+e

    f16x4 hn[6][4];
#pragma unroll
    for (int n = 0; n < 6; ++n) {
      f32x4 acc[4];
#pragma unroll
      for (int nt = 0; nt < 4; ++nt) acc[nt] = bval[nt];
#pragma unroll
      for (int kc = 0; kc < 4; ++kc) {
        // aggregate in f16 B-frag space (identical layouts across nodes)
        f16x4 ag = h[n][kc] + h[NB0[n]][kc] + h[NB1[n]][kc];
        if (l >= 2) ag = ag + h[n][kc];   // improved: self coeff = 2*cb
#pragma unroll
        for (int nt = 0; nt < 4; ++nt)
          acc[nt] = __builtin_amdgcn_mfma_f32_16x16x16f16(wf[nt][kc], ag, acc[nt], 0, 0, 0);
      }
      if (l < 3) {
        // relu + f32->f16: C-frag (rows 4q+e) IS next layer's B-frag (k 4q+j)
#pragma unroll
        for (int nt = 0; nt < 4; ++nt) {
          f32x4 r;
#pragma unroll
          for (int e = 0; e < 4; ++e) r[e] = fmaxf(acc[nt][e], 0.f);
          hn[n][nt] = cvt4(r);
        }
      } else {
        // layer 4 epilogue: relu + fc-dot in f32, reduce over q, sigmoid, store
        float sv = pacc[n];
#pragma unroll
        for (int nt = 0; nt < 4; ++nt) {
          f32x4 fwv = *(const f32x4*)(fcw + n * 64 + nt * 16 + q * 4);
#pragma unroll
          for (int e = 0; e < 4; ++e) sv += fmaxf(acc[nt][e], 0.f) * fwv[e];
        }
        sv += __shfl_xor(sv, 16, 64);
        sv += __shfl_xor(sv, 32, 64);
        if (q == 0) {
          const float vz = sv + fcb[n];
          out[(size_t)b * 6 + n] = 1.f / (1.f + __expf(-vz));
        }
      }
    }
    if (l < 3) {
#pragma unroll
      for (int n = 0; n < 6; ++n)
#pragma unroll
        for (int kc = 0; kc < 4; ++kc) h[n][kc] = hn[n][kc];
    }
  }
}

extern "C" void kernel_launch(void* const* d_in, const int* in_sizes, int n_in,
                              void* d_out, int out_size, void* d_ws, size_t ws_size,
                              hipStream_t stream) {
  const float* x   = (const float*)d_in[0];
  const float* W1  = (const float*)d_in[1];
  const float* B1  = (const float*)d_in[2];
  const float* W2  = (const float*)d_in[3];
  const float* B2  = (const float*)d_in[4];
  const float* W3  = (const float*)d_in[5];
  const float* B3  = (const float*)d_in[6];
  const float* W4  = (const float*)d_in[7];
  const float* B4  = (const float*)d_in[8];
  const float* fcw = (const float*)d_in[9];
  const float* fcb = (const float*)d_in[10];
  float* out = (float*)d_out;

  const int batch  = in_sizes[0] / 384;   // 131072
  const int blocks = batch / 64;          // 4 waves x 16 batch rows per block
  hipLaunchKernelGGL(gcn_fused, dim3(blocks), dim3(256), 0, stream,
                     x, W1, B1, W2, B2, W3, B3, W4, B4, fcw, fcb, out);
}

// Round 9
// 113.740 us; speedup vs baseline: 1.7128x; 1.5709x over previous
//
#include <hip/hip_runtime.h>

typedef __attribute__((ext_vector_type(4))) _Float16 f16x4;
typedef __attribute__((ext_vector_type(2))) __fp16 fp16x2;
typedef __attribute__((ext_vector_type(4))) float f32x4;

union U4 { f16x4 v; fp16x2 p[2]; };

__device__ __forceinline__ f16x4 cvt4(f32x4 a) {
  U4 u;
  u.p[0] = __builtin_amdgcn_cvt_pkrtz(a.x, a.y);
  u.p[1] = __builtin_amdgcn_cvt_pkrtz(a.z, a.w);
  return u.v;
}
__device__ __forceinline__ float dot4(f32x4 a, f32x4 b) {
  return a.x * b.x + a.y * b.y + a.z * b.z + a.w * b.w;
}

#define WSTRIDE 72  // f16 row stride: 144B rows, near-conflict-free b64 frag reads

// Zero-data-movement GCN: wave-private 16 batch rows, K=16 MFMA B<->C chaining
// (C rows 4q+e == B k 4q+j), aggregate-BEFORE-matmul in f16 B-frag space
// (1x FLOPs): out[n] = relu( (cb*W) . ag[n] + b ),
//   ag[n] = h[n]*(1 or 2) + h[m1] + h[m2]   (cb pre-folded into W in LDS).
// (256,2): ~180 VGPRs of live state NEEDS the 256-reg budget — (256,3) spilled
// 300MB of scratch traffic in r8 (WRITE_SIZE counter). Do not tighten.
__global__ __launch_bounds__(256, 2) void gcn_fused(
    const float* __restrict__ x,
    const float* __restrict__ W1, const float* __restrict__ B1,
    const float* __restrict__ W2, const float* __restrict__ B2,
    const float* __restrict__ W3, const float* __restrict__ B3,
    const float* __restrict__ W4, const float* __restrict__ B4,
    const float* __restrict__ fcw, const float* __restrict__ fcb,
    float* __restrict__ out)
{
  __shared__ __align__(16) _Float16 wlds[4][64][WSTRIDE];  // cb_l * W_l

  const int tid  = threadIdx.x;
  const int lane = tid & 63;
  const int w    = tid >> 6;
  const int c    = lane & 15;   // batch col (B/C col, A row)
  const int q    = lane >> 4;   // k-group (k=4q+j) / C row-group (row=4q+e)
  const int b    = blockIdx.x * 64 + w * 16 + c;   // this lane's batch row

  const float* Wg[4] = {W1, W2, W3, W4};
  const float* Bg[4] = {B1, B2, B3, B4};
  const int NB0[6] = {1, 0, 1, 2, 3, 3};
  const int NB1[6] = {2, 2, 3, 4, 5, 4};

  // ---- stage cb_l * W_l into LDS (once, all 4 layers) ----
#pragma unroll
  for (int l = 0; l < 4; ++l) {
    const float s = (l < 2) ? (1.f / 3.f) : 0.25f;
#pragma unroll
    for (int rep = 0; rep < 4; ++rep) {
      const int idx = rep * 1024 + tid * 4;   // flat f32 index into 64x64 W_l
      const int row = idx >> 6, col = idx & 63;
      f32x4 v = *(const f32x4*)(Wg[l] + idx);
      v *= s;
      *(f16x4*)&wlds[l][row][col] = cvt4(v);
    }
  }

  // ---- x -> layer-1 B-frags (registers) + residual fc-dot q-partials ----
  f16x4 h[6][4];   // [node][kc]: lane (c,q) holds feats kc*16+4q+j of batch b
  float pacc[6];
  {
    const float* xr = x + (size_t)b * 384 + q * 4;
#pragma unroll
    for (int n = 0; n < 6; ++n) {
      float p = 0.f;
#pragma unroll
      for (int kc = 0; kc < 4; ++kc) {
        f32x4 v  = *(const f32x4*)(xr + n * 64 + kc * 16);
        f32x4 fw = *(const f32x4*)(fcw + n * 64 + kc * 16 + q * 4);
        p += dot4(v, fw);
        h[n][kc] = cvt4(v);
      }
      pacc[n] = p;  // partial over this lane's 16 k-values; reduced at epilogue
    }
  }
  __syncthreads();  // W staging visible; no further barriers

#pragma unroll
  for (int l = 0; l < 4; ++l) {
    // W A-frags from LDS: lane (c,q): row = nt*16+c, k = kc*16+4q+j
    f16x4 wf[4][4];
#pragma unroll
    for (int nt = 0; nt < 4; ++nt)
#pragma unroll
      for (int kc = 0; kc < 4; ++kc)
        wf[nt][kc] = *(const f16x4*)&wlds[l][nt * 16 + c][kc * 16 + q * 4];
    f32x4 bval[4];
#pragma unroll
    for (int nt = 0; nt < 4; ++nt)
      bval[nt] = *(const f32x4*)(Bg[l] + nt * 16 + q * 4);  // bias rows nt*16+4q+e

    f16x4 hn[6][4];
#pragma unroll
    for (int n = 0; n < 6; ++n) {
      f32x4 acc[4];
#pragma unroll
      for (int nt = 0; nt < 4; ++nt) acc[nt] = bval[nt];
#pragma unroll
      for (int kc = 0; kc < 4; ++kc) {
        // aggregate in f16 B-frag space (identical layouts across nodes)
        f16x4 ag = h[n][kc] + h[NB0[n]][kc] + h[NB1[n]][kc];
        if (l >= 2) ag = ag + h[n][kc];   // improved: self coeff = 2*cb
#pragma unroll
        for (int nt = 0; nt < 4; ++nt)
          acc[nt] = __builtin_amdgcn_mfma_f32_16x16x16f16(wf[nt][kc], ag, acc[nt], 0, 0, 0);
      }
      if (l < 3) {
        // relu + f32->f16: C-frag (rows 4q+e) IS next layer's B-frag (k 4q+j)
#pragma unroll
        for (int nt = 0; nt < 4; ++nt) {
          f32x4 r;
#pragma unroll
          for (int e = 0; e < 4; ++e) r[e] = fmaxf(acc[nt][e], 0.f);
          hn[n][nt] = cvt4(r);
        }
      } else {
        // layer 4 epilogue: relu + fc-dot in f32, reduce over q, sigmoid, store
        float sv = pacc[n];
#pragma unroll
        for (int nt = 0; nt < 4; ++nt) {
          f32x4 fwv = *(const f32x4*)(fcw + n * 64 + nt * 16 + q * 4);
#pragma unroll
          for (int e = 0; e < 4; ++e) sv += fmaxf(acc[nt][e], 0.f) * fwv[e];
        }
        sv += __shfl_xor(sv, 16, 64);
        sv += __shfl_xor(sv, 32, 64);
        if (q == 0) {
          const float vz = sv + fcb[n];
          out[(size_t)b * 6 + n] = 1.f / (1.f + __expf(-vz));
        }
      }
    }
    if (l < 3) {
#pragma unroll
      for (int n = 0; n < 6; ++n)
#pragma unroll
        for (int kc = 0; kc < 4; ++kc) h[n][kc] = hn[n][kc];
    }
  }
}

extern "C" void kernel_launch(void* const* d_in, const int* in_sizes, int n_in,
                              void* d_out, int out_size, void* d_ws, size_t ws_size,
                              hipStream_t stream) {
  const float* x   = (const float*)d_in[0];
  const float* W1  = (const float*)d_in[1];
  const float* B1  = (const float*)d_in[2];
  const float* W2  = (const float*)d_in[3];
  const float* B2  = (const float*)d_in[4];
  const float* W3  = (const float*)d_in[5];
  const float* B3  = (const float*)d_in[6];
  const float* W4  = (const float*)d_in[7];
  const float* B4  = (const float*)d_in[8];
  const float* fcw = (const float*)d_in[9];
  const float* fcb = (const float*)d_in[10];
  float* out = (float*)d_out;

  const int batch  = in_sizes[0] / 384;   // 131072
  const int blocks = batch / 64;          // 4 waves x 16 batch rows per block
  hipLaunchKernelGGL(gcn_fused, dim3(blocks), dim3(256), 0, stream,
                     x, W1, B1, W2, B2, W3, B3, W4, B4, fcw, fcb, out);
}